// Round 1
// baseline (191.608 us; speedup 1.0000x reference)
//
#include <hip/hip_runtime.h>

// CrossHeadProjectionV2: B=1, N=16, T=S=2048, G=1, I=2, M=16.
// out[n,t,s] = sum_m x[m,t,s]*wq[t][m][n]
//            + sum_i kw2[s,i,n] * (sum_m x[m,t,s]*kw1[s,i,m])
//            + x[n,t,s]*kdd[s,n]
// where wq folds w+I, qdd diagonal, and the rank-2 q-side update (t-only deps).

#define TDIM 2048
#define SDIM 2048

// ---- prep: transpose per-s weights to s-minor for coalesced float4 reads ----
// kt1[i*16+m][s] = kw1[s][i][m]   (2*16*2048 floats)
// kt2[i*16+n][s] = kw2[s][i][n]   (2*16*2048 floats)
// kddt[n][s]     = kdd[s][n]      (16*2048 floats)
__global__ void chp_prep(const float* __restrict__ kw1, const float* __restrict__ kw2,
                         const float* __restrict__ kdd,
                         float* __restrict__ kt1, float* __restrict__ kt2,
                         float* __restrict__ kddt) {
  int tid = blockIdx.x * blockDim.x + threadIdx.x;  // 0 .. 163839
  if (tid < 65536) {
    int im = tid >> 11, s = tid & 2047;
    kt1[tid] = kw1[s * 32 + im];
  } else if (tid < 131072) {
    int v = tid - 65536;
    int im = v >> 11, s = v & 2047;
    kt2[v] = kw2[s * 32 + im];
  } else if (tid < 163840) {
    int v = tid - 131072;
    int n = v >> 11, s = v & 2047;
    kddt[v] = kdd[s * 16 + n];
  }
}

__device__ __forceinline__ float4 ld4(const float* p) {
  return *reinterpret_cast<const float4*>(p);
}
__device__ __forceinline__ void fma4(float4& d, const float4& a, const float4& b) {
  d.x = fmaf(a.x, b.x, d.x);
  d.y = fmaf(a.y, b.y, d.y);
  d.z = fmaf(a.z, b.z, d.z);
  d.w = fmaf(a.w, b.w, d.w);
}
__device__ __forceinline__ void fma4s(float4& d, const float4& a, float b) {
  d.x = fmaf(a.x, b, d.x);
  d.y = fmaf(a.y, b, d.y);
  d.z = fmaf(a.z, b, d.z);
  d.w = fmaf(a.w, b, d.w);
}

// grid = (2, 2048): blockIdx.y = t, blockIdx.x = s-slab of 1024.
// 256 threads; thread owns 4 consecutive s (float4 everywhere).
template <bool KT>
__global__ __launch_bounds__(256, 2) void chp_main(
    const float* __restrict__ in, const float* __restrict__ w,
    const float* __restrict__ qw1, const float* __restrict__ qw2,
    const float* __restrict__ qdd, const float* __restrict__ kw1,
    const float* __restrict__ kw2, const float* __restrict__ kdd,
    const float* __restrict__ kt1, const float* __restrict__ kt2,
    const float* __restrict__ kddt, float* __restrict__ out) {
  __shared__ float wq_s[256];  // wq[m][n] for this t
  const int t = blockIdx.y;
  const int tid = threadIdx.x;

  {  // build wq[t]: one entry per thread
    int m = tid >> 4, n = tid & 15;
    float v = w[m * 16 + n];
    v = fmaf(qw1[t * 32 + m], qw2[t * 32 + n], v);            // i = 0
    v = fmaf(qw1[t * 32 + 16 + m], qw2[t * 32 + 16 + n], v);  // i = 1
    if (m == n) v += 1.0f + qdd[t * 16 + n];                  // identity + q-diag
    wq_s[tid] = v;
  }
  __syncthreads();

  const int s0 = blockIdx.x * 1024 + tid * 4;

  float4 acc[16];
  float4 hk0 = make_float4(0.f, 0.f, 0.f, 0.f);
  float4 hk1 = make_float4(0.f, 0.f, 0.f, 0.f);
#pragma unroll
  for (int n = 0; n < 16; ++n) acc[n] = make_float4(0.f, 0.f, 0.f, 0.f);

#pragma unroll
  for (int m = 0; m < 16; ++m) {
    const float4 x = ld4(in + ((size_t)m * TDIM + t) * SDIM + s0);
    float4 k1a, k1b, kd;
    if constexpr (KT) {
      k1a = ld4(kt1 + (size_t)m * SDIM + s0);
      k1b = ld4(kt1 + (size_t)(16 + m) * SDIM + s0);
      kd = ld4(kddt + (size_t)m * SDIM + s0);
    } else {
      k1a = make_float4(kw1[(size_t)(s0 + 0) * 32 + m], kw1[(size_t)(s0 + 1) * 32 + m],
                        kw1[(size_t)(s0 + 2) * 32 + m], kw1[(size_t)(s0 + 3) * 32 + m]);
      k1b = make_float4(kw1[(size_t)(s0 + 0) * 32 + 16 + m], kw1[(size_t)(s0 + 1) * 32 + 16 + m],
                        kw1[(size_t)(s0 + 2) * 32 + 16 + m], kw1[(size_t)(s0 + 3) * 32 + 16 + m]);
      kd = make_float4(kdd[(size_t)(s0 + 0) * 16 + m], kdd[(size_t)(s0 + 1) * 16 + m],
                       kdd[(size_t)(s0 + 2) * 16 + m], kdd[(size_t)(s0 + 3) * 16 + m]);
    }
    fma4(hk0, x, k1a);     // hk[0] += x[m]*kw1[s,0,m]
    fma4(hk1, x, k1b);     // hk[1] += x[m]*kw1[s,1,m]
    fma4(acc[m], x, kd);   // k-diag: acc[n=m] += x[m]*kdd[s,m]
    const float* wr = &wq_s[m * 16];
#pragma unroll
    for (int n = 0; n < 16; ++n) fma4s(acc[n], x, wr[n]);  // broadcast LDS read
  }

#pragma unroll
  for (int n = 0; n < 16; ++n) {
    float4 k2a, k2b;
    if constexpr (KT) {
      k2a = ld4(kt2 + (size_t)n * SDIM + s0);
      k2b = ld4(kt2 + (size_t)(16 + n) * SDIM + s0);
    } else {
      k2a = make_float4(kw2[(size_t)(s0 + 0) * 32 + n], kw2[(size_t)(s0 + 1) * 32 + n],
                        kw2[(size_t)(s0 + 2) * 32 + n], kw2[(size_t)(s0 + 3) * 32 + n]);
      k2b = make_float4(kw2[(size_t)(s0 + 0) * 32 + 16 + n], kw2[(size_t)(s0 + 1) * 32 + 16 + n],
                        kw2[(size_t)(s0 + 2) * 32 + 16 + n], kw2[(size_t)(s0 + 3) * 32 + 16 + n]);
    }
    fma4(acc[n], hk0, k2a);
    fma4(acc[n], hk1, k2b);
    *reinterpret_cast<float4*>(out + ((size_t)n * TDIM + t) * SDIM + s0) = acc[n];
  }
}

extern "C" void kernel_launch(void* const* d_in, const int* in_sizes, int n_in,
                              void* d_out, int out_size, void* d_ws, size_t ws_size,
                              hipStream_t stream) {
  const float* in = (const float*)d_in[0];
  const float* qw1 = (const float*)d_in[1];
  const float* qw2 = (const float*)d_in[2];
  const float* kw1 = (const float*)d_in[3];
  const float* kw2 = (const float*)d_in[4];
  const float* qdd = (const float*)d_in[5];
  const float* kdd = (const float*)d_in[6];
  const float* w = (const float*)d_in[7];
  float* out = (float*)d_out;
  float* ws = (float*)d_ws;

  const bool useKT = (ws_size >= 163840ull * sizeof(float));
  float* kt1 = ws;
  float* kt2 = ws + 65536;
  float* kddt = ws + 131072;

  dim3 grid(2, 2048);
  if (useKT) {
    hipLaunchKernelGGL(chp_prep, dim3(640), dim3(256), 0, stream, kw1, kw2, kdd, kt1,
                       kt2, kddt);
    hipLaunchKernelGGL((chp_main<true>), grid, dim3(256), 0, stream, in, w, qw1, qw2,
                       qdd, kw1, kw2, kdd, kt1, kt2, kddt, out);
  } else {
    hipLaunchKernelGGL((chp_main<false>), grid, dim3(256), 0, stream, in, w, qw1, qw2,
                       qdd, kw1, kw2, kdd, nullptr, nullptr, nullptr, out);
  }
}